// Round 1
// baseline (228.827 us; speedup 1.0000x reference)
//
#include <hip/hip_runtime.h>
#include <hip/hip_bf16.h>
#include <math.h>

#define NPTS   8192
#define BITS   64
#define NCLS   101
#define TILE   128
#define NT     (NPTS / TILE)            // 64
#define NPAIRS (NT * (NT + 1) / 2)      // 2080
#define CLS_BLOCKS 256

// ws layout (doubles):
//   [0, NPAIRS)                : pos partial sums (same-class pairs, i<j)
//   [NPAIRS, 2*NPAIRS)         : neg partial sums (diff-class pairs, i<j)
//   [2*NPAIRS, 2*NPAIRS+256)   : cls partial sums

// ---------------------------------------------------------------------------
// Kernel 1: per-row log-softmax NLL, one wave (64 lanes) per row.
// ---------------------------------------------------------------------------
__global__ __launch_bounds__(256) void cls_kernel(const float* __restrict__ X,
                                                  const int* __restrict__ tgt,
                                                  double* __restrict__ ws) {
    const int tid  = threadIdx.x;
    const int lane = tid & 63;
    const int wave = tid >> 6;
    __shared__ float wsum[4];

    float acc = 0.f;
    const int row0 = blockIdx.x * 32 + wave * 8;
    for (int rr = 0; rr < 8; rr++) {
        const int row = row0 + rr;
        const float* x = X + (size_t)row * NCLS;
        float x1 = x[lane];
        float x2 = (lane + 64 < NCLS) ? x[lane + 64] : -INFINITY;
        float m = fmaxf(x1, x2);
#pragma unroll
        for (int d = 32; d > 0; d >>= 1) m = fmaxf(m, __shfl_xor(m, d, 64));
        float e = expf(x1 - m) + ((lane + 64 < NCLS) ? expf(x2 - m) : 0.f);
#pragma unroll
        for (int d = 32; d > 0; d >>= 1) e += __shfl_xor(e, d, 64);
        if (lane == 0) {
            float xt = x[tgt[row]];
            acc += m + logf(e) - xt;   // -log_softmax[target]
        }
    }
    if (lane == 0) wsum[wave] = acc;
    __syncthreads();
    if (tid == 0) {
        double s = (double)wsum[0] + (double)wsum[1] + (double)wsum[2] + (double)wsum[3];
        ws[2 * NPAIRS + blockIdx.x] = s;
    }
}

// ---------------------------------------------------------------------------
// Kernel 2: pairwise hash loss over upper-triangular 128x128 tiles.
// theta = H H^T / 2 computed with fp32 FMAs; LDS tiles stored k-major with an
// XOR-(k&31) column swizzle -> conflict-free staging writes AND fragment reads.
// Each thread owns an 8x8 micro-tile (strided by 16). Accumulates two sums:
// pos = sum(softplus(th) - th) over same-class i<j, neg = sum(softplus(th)).
// ---------------------------------------------------------------------------
__global__ __launch_bounds__(256, 2) void hash_pair_kernel(const float* __restrict__ H,
                                                           const int* __restrict__ tgt,
                                                           double* __restrict__ ws) {
    __shared__ float As[64 * TILE];
    __shared__ float Bs[64 * TILE];

    const int tid = threadIdx.x;
    const int tx = tid & 15;
    const int ty = tid >> 4;

    // map linear block id -> (ti, tj) with ti <= tj
    const int p = blockIdx.x;
    int ti;
    {
        float disc = (2.0f * NT + 1.0f) * (2.0f * NT + 1.0f) - 8.0f * (float)p;
        ti = (int)(((2.0f * NT + 1.0f) - sqrtf(disc)) * 0.5f);
        if (ti < 0) ti = 0;
        if (ti >= NT) ti = NT - 1;
        while (ti > 0 && (ti * NT - ti * (ti - 1) / 2) > p) ti--;
        while ((ti + 1) * NT - (ti + 1) * ti / 2 <= p) ti++;
    }
    const int base = ti * NT - ti * (ti - 1) / 2;
    const int tj = ti + (p - base);
    const int i0 = ti * TILE;
    const int j0 = tj * TILE;

    // stage both tiles: global reads coalesced (consecutive t -> consecutive addr)
    for (int t = tid; t < TILE * 64; t += 256) {
        const int row = t >> 6;
        const int k   = t & 63;
        const int sw  = k & 31;
        As[k * TILE + (row ^ sw)] = H[(size_t)(i0 + row) * BITS + k];
        Bs[k * TILE + (row ^ sw)] = H[(size_t)(j0 + row) * BITS + k];
    }

    int trow[8], tcol[8];
#pragma unroll
    for (int r = 0; r < 8; r++) trow[r] = tgt[i0 + ty + 16 * r];
#pragma unroll
    for (int c = 0; c < 8; c++) tcol[c] = tgt[j0 + tx + 16 * c];

    __syncthreads();

    float acc[8][8];
#pragma unroll
    for (int r = 0; r < 8; r++)
#pragma unroll
        for (int c = 0; c < 8; c++) acc[r][c] = 0.f;

    for (int k = 0; k < 64; k++) {
        const int sw = k & 31;
        float a[8], b[8];
#pragma unroll
        for (int r = 0; r < 8; r++) a[r] = As[k * TILE + ((ty + 16 * r) ^ sw)];
#pragma unroll
        for (int c = 0; c < 8; c++) b[c] = Bs[k * TILE + ((tx + 16 * c) ^ sw)];
#pragma unroll
        for (int r = 0; r < 8; r++)
#pragma unroll
            for (int c = 0; c < 8; c++) acc[r][c] = fmaf(a[r], b[c], acc[r][c]);
    }

    // epilogue: softplus + class-match split, only i<j
    float pos = 0.f, neg = 0.f;
#pragma unroll
    for (int r = 0; r < 8; r++) {
        const int i = i0 + ty + 16 * r;
#pragma unroll
        for (int c = 0; c < 8; c++) {
            const int j = j0 + tx + 16 * c;
            if (j > i) {
                float th = 0.5f * acc[r][c];
                float sp = log1pf(expf(th));   // faithful unstabilized softplus
                if (trow[r] == tcol[c]) pos += sp - th;
                else                    neg += sp;
            }
        }
    }

    __syncthreads();
    float* red = As;  // reuse LDS
    red[tid]       = pos;
    red[256 + tid] = neg;
    __syncthreads();
    for (int s = 128; s > 0; s >>= 1) {
        if (tid < s) {
            red[tid]       += red[tid + s];
            red[256 + tid] += red[256 + tid + s];
        }
        __syncthreads();
    }
    if (tid == 0) {
        ws[blockIdx.x]          = (double)red[0];
        ws[NPAIRS + blockIdx.x] = (double)red[256];
    }
}

// ---------------------------------------------------------------------------
// Kernel 3: finalize. Class histogram -> n_pos -> S0/S1 weights; reduce all
// partials in double; write the 3 output scalars.
// ---------------------------------------------------------------------------
__global__ __launch_bounds__(256) void final_kernel(const int* __restrict__ tgt,
                                                    const double* __restrict__ ws,
                                                    float* __restrict__ out) {
    __shared__ int hist[NCLS];
    __shared__ double redp[256], redn[256], redc[256];
    const int tid = threadIdx.x;

    for (int i = tid; i < NCLS; i += 256) hist[i] = 0;
    __syncthreads();
    for (int i = tid; i < NPTS; i += 256) atomicAdd(&hist[tgt[i]], 1);
    __syncthreads();

    double p = 0.0, n = 0.0, c = 0.0;
    for (int i = tid; i < NPAIRS; i += 256) { p += ws[i]; n += ws[NPAIRS + i]; }
    for (int i = tid; i < CLS_BLOCKS; i += 256) c += ws[2 * NPAIRS + i];
    redp[tid] = p; redn[tid] = n; redc[tid] = c;
    __syncthreads();
    for (int s = 128; s > 0; s >>= 1) {
        if (tid < s) {
            redp[tid] += redp[tid + s];
            redn[tid] += redn[tid + s];
            redc[tid] += redc[tid + s];
        }
        __syncthreads();
    }

    if (tid == 0) {
        double n_pos = 0.0;
        for (int k = 0; k < NCLS; k++) {
            double cc = (double)hist[k];
            n_pos += cc * cc;
        }
        const double Nd = (double)NPTS;
        double S1 = n_pos - Nd;
        double S0 = Nd * Nd - n_pos;
        if (S0 == 0.0) S0 = 1.0;
        if (S1 == 0.0) S1 = 1.0;
        const double S = S0 + S1;
        // sum over ordered pairs = 2 * lower-sum; hash = total/2/count = lower/count
        const double sum_lower = (S / S1) * redp[0] + (S / S0) * redn[0];
        const double count = Nd * (Nd - 1.0) * 0.5;
        const double hash_loss = sum_lower / count;
        const double cls_loss  = redc[0] / Nd;
        const double loss = 1.0 * cls_loss + 0.01 * hash_loss;
        out[0] = (float)hash_loss;
        out[1] = (float)cls_loss;
        out[2] = (float)loss;
    }
}

// ---------------------------------------------------------------------------
extern "C" void kernel_launch(void* const* d_in, const int* in_sizes, int n_in,
                              void* d_out, int out_size, void* d_ws, size_t ws_size,
                              hipStream_t stream) {
    const float* H   = (const float*)d_in[0];   // hash_out [8192,64]
    const float* X   = (const float*)d_in[1];   // cls_out  [8192,101]
    const int*   tgt = (const int*)d_in[2];     // target   [8192]
    float* out = (float*)d_out;
    double* wsd = (double*)d_ws;

    cls_kernel<<<CLS_BLOCKS, 256, 0, stream>>>(X, tgt, wsd);
    hash_pair_kernel<<<NPAIRS, 256, 0, stream>>>(H, tgt, wsd);
    final_kernel<<<1, 256, 0, stream>>>(tgt, wsd, out);
}

// Round 2
// 53.615 us; speedup vs baseline: 4.2679x; 4.2679x over previous
//
#include <hip/hip_runtime.h>
#include <math.h>

#define NPTS   8192
#define BITS   64
#define NCLS   101
#define TILE   128
#define NT     (NPTS / TILE)            // 64
#define NPAIRS (NT * (NT + 1) / 2)      // 2080
#define CLS_BLOCKS 256
#define WS_CLS (3 * NPAIRS)

// ws layout (doubles):
//   [0, NPAIRS)            : SP_all  partial sums (softplus over all i<j in tile)
//   [NPAIRS, 2*NPAIRS)     : SP_same partial sums (softplus over same-class i<j)
//   [2*NPAIRS, 3*NPAIRS)   : TH_same partial sums (theta over same-class i<j)
//   [WS_CLS, WS_CLS+256)   : cls partial sums

typedef short    bf16x8  __attribute__((ext_vector_type(8)));
typedef unsigned short ushort8v __attribute__((ext_vector_type(8)));
typedef float    f32x16  __attribute__((ext_vector_type(16)));

__device__ __forceinline__ unsigned short f2bf(float f) {
    unsigned int u = __float_as_uint(f);
    u += 0x7FFFu + ((u >> 16) & 1u);     // round-to-nearest-even (inputs are finite)
    return (unsigned short)(u >> 16);
}

// ---------------------------------------------------------------------------
// Kernel 1: per-row log-softmax NLL, one wave (64 lanes) per row.
// ---------------------------------------------------------------------------
__global__ __launch_bounds__(256) void cls_kernel(const float* __restrict__ X,
                                                  const int* __restrict__ tgt,
                                                  double* __restrict__ ws) {
    const int tid  = threadIdx.x;
    const int lane = tid & 63;
    const int wave = tid >> 6;
    __shared__ float wsum[4];

    float acc = 0.f;
    const int row0 = blockIdx.x * 32 + wave * 8;
    for (int rr = 0; rr < 8; rr++) {
        const int row = row0 + rr;
        const float* x = X + (size_t)row * NCLS;
        float x1 = x[lane];
        float x2 = (lane + 64 < NCLS) ? x[lane + 64] : -INFINITY;
        float m = fmaxf(x1, x2);
#pragma unroll
        for (int d = 32; d > 0; d >>= 1) m = fmaxf(m, __shfl_xor(m, d, 64));
        float e = expf(x1 - m) + ((lane + 64 < NCLS) ? expf(x2 - m) : 0.f);
#pragma unroll
        for (int d = 32; d > 0; d >>= 1) e += __shfl_xor(e, d, 64);
        if (lane == 0) {
            float xt = x[tgt[row]];
            acc += m + logf(e) - xt;   // -log_softmax[target]
        }
    }
    if (lane == 0) wsum[wave] = acc;
    __syncthreads();
    if (tid == 0) {
        double s = (double)wsum[0] + (double)wsum[1] + (double)wsum[2] + (double)wsum[3];
        ws[WS_CLS + blockIdx.x] = s;
    }
}

// ---------------------------------------------------------------------------
// Kernel 2: pairwise hash loss, MFMA version.
// Per block: one 128x128 upper-triangular tile of theta = H H^T / 2.
// Stage fp32 -> bf16 into XOR-swizzled LDS (byte ^= (row&7)<<4 equivalent);
// 4 waves in 2x2, each computes a 64x64 tile as 2x2 mfma_f32_32x32x16_bf16
// tiles over K=64 (4 k-steps). Epilogue: softplus via __expf/__logf with
// three accumulators; weights applied in finalize.
// ---------------------------------------------------------------------------
__global__ __launch_bounds__(256) void hash_pair_kernel(const float* __restrict__ H,
                                                        const int* __restrict__ tgt,
                                                        double* __restrict__ ws) {
    __shared__ unsigned short As[TILE * BITS];   // 16 KiB, swizzled bf16
    __shared__ unsigned short Bs[TILE * BITS];   // 16 KiB
    __shared__ int tI[TILE];
    __shared__ int tJ[TILE];
    __shared__ float red[12];

    const int tid = threadIdx.x;

    // map linear block id -> (ti, tj) with ti <= tj
    const int p = blockIdx.x;
    int ti;
    {
        float disc = (2.0f * NT + 1.0f) * (2.0f * NT + 1.0f) - 8.0f * (float)p;
        ti = (int)(((2.0f * NT + 1.0f) - sqrtf(disc)) * 0.5f);
        if (ti < 0) ti = 0;
        if (ti >= NT) ti = NT - 1;
        while (ti > 0 && (ti * NT - ti * (ti - 1) / 2) > p) ti--;
        while ((ti + 1) * NT - (ti + 1) * ti / 2 <= p) ti++;
    }
    const int base = ti * NT - ti * (ti - 1) / 2;
    const int tj = ti + (p - base);
    const int i0 = ti * TILE;
    const int j0 = tj * TILE;

    if (tid < TILE) { tI[tid] = tgt[i0 + tid]; tJ[tid] = tgt[j0 + tid]; }

    // stage both tiles as bf16: 2048 chunks of 8 elements (16B LDS each)
#pragma unroll
    for (int it = 0; it < 8; ++it) {
        int idx  = tid + it * 256;
        int half = idx >> 10;          // 0 -> A rows, 1 -> B rows
        int lid  = idx & 1023;
        int row  = lid >> 3;
        int c    = lid & 7;            // 8-element chunk within the 64-wide row
        const float* src = H + (size_t)((half ? j0 : i0) + row) * BITS + c * 8;
        float4 f0 = *(const float4*)src;
        float4 f1 = *(const float4*)(src + 4);
        ushort8v v;
        v[0] = f2bf(f0.x); v[1] = f2bf(f0.y); v[2] = f2bf(f0.z); v[3] = f2bf(f0.w);
        v[4] = f2bf(f1.x); v[5] = f2bf(f1.y); v[6] = f2bf(f1.z); v[7] = f2bf(f1.w);
        unsigned short* dst = half ? Bs : As;
        *(ushort8v*)&dst[row * BITS + ((c ^ (row & 7)) * 8)] = v;
    }
    __syncthreads();

    const int lane = tid & 63;
    const int wave = tid >> 6;
    const int wr = wave >> 1, wc = wave & 1;   // 2x2 wave grid, 64x64 each
    const int lrow = lane & 31;
    const int hi = lane >> 5;                  // k-half selector

    f32x16 acc[2][2];
#pragma unroll
    for (int a = 0; a < 2; ++a)
#pragma unroll
        for (int b = 0; b < 2; ++b)
#pragma unroll
            for (int e = 0; e < 16; ++e) acc[a][b][e] = 0.f;

    // fragment: lane holds row (l&31) of a 32-row strip, k = ks*16 + hi*8 + e
    auto ldfrag = [](const unsigned short* S, int row, int chunk) -> bf16x8 {
        ushort8v r = *(const ushort8v*)&S[row * BITS + ((chunk ^ (row & 7)) * 8)];
        return __builtin_bit_cast(bf16x8, r);
    };

#pragma unroll
    for (int ks = 0; ks < 4; ++ks) {
        const int ch = ks * 2 + hi;
        bf16x8 a0 = ldfrag(As, wr * 64 +      lrow, ch);
        bf16x8 a1 = ldfrag(As, wr * 64 + 32 + lrow, ch);
        bf16x8 b0 = ldfrag(Bs, wc * 64 +      lrow, ch);
        bf16x8 b1 = ldfrag(Bs, wc * 64 + 32 + lrow, ch);
        acc[0][0] = __builtin_amdgcn_mfma_f32_32x32x16_bf16(a0, b0, acc[0][0], 0, 0, 0);
        acc[0][1] = __builtin_amdgcn_mfma_f32_32x32x16_bf16(a0, b1, acc[0][1], 0, 0, 0);
        acc[1][0] = __builtin_amdgcn_mfma_f32_32x32x16_bf16(a1, b0, acc[1][0], 0, 0, 0);
        acc[1][1] = __builtin_amdgcn_mfma_f32_32x32x16_bf16(a1, b1, acc[1][1], 0, 0, 0);
    }

    // epilogue: C/D layout col = lane&31, row = (reg&3) + 8*(reg>>2) + 4*(lane>>5)
    float sp_all = 0.f, sp_same = 0.f, th_same = 0.f;
#pragma unroll
    for (int it = 0; it < 2; ++it) {
        int trow[16], grow[16];
#pragma unroll
        for (int r = 0; r < 16; ++r) {
            int lr = wr * 64 + it * 32 + (r & 3) + 8 * (r >> 2) + 4 * hi;
            grow[r] = i0 + lr;
            trow[r] = tI[lr];
        }
#pragma unroll
        for (int jt = 0; jt < 2; ++jt) {
            const int lc = wc * 64 + jt * 32 + lrow;
            const int gcol = j0 + lc;
            const int tc = tJ[lc];
#pragma unroll
            for (int r = 0; r < 16; ++r) {
                float th = 0.5f * acc[it][jt][r];
                float sp = __logf(1.0f + __expf(th));
                bool valid = gcol > grow[r];
                bool same = valid && (trow[r] == tc);
                sp_all  += valid ? sp : 0.0f;
                sp_same += same ? sp : 0.0f;
                th_same += same ? th : 0.0f;
            }
        }
    }

    // wave reduce then cross-wave
#pragma unroll
    for (int d = 32; d > 0; d >>= 1) {
        sp_all  += __shfl_xor(sp_all,  d, 64);
        sp_same += __shfl_xor(sp_same, d, 64);
        th_same += __shfl_xor(th_same, d, 64);
    }
    if (lane == 0) { red[wave] = sp_all; red[4 + wave] = sp_same; red[8 + wave] = th_same; }
    __syncthreads();
    if (tid == 0) {
        ws[p] = (double)red[0] + (double)red[1] + (double)red[2] + (double)red[3];
        ws[NPAIRS + p] = (double)red[4] + (double)red[5] + (double)red[6] + (double)red[7];
        ws[2 * NPAIRS + p] = (double)red[8] + (double)red[9] + (double)red[10] + (double)red[11];
    }
}

// ---------------------------------------------------------------------------
// Kernel 3: finalize. Class histogram -> n_pos -> S0/S1 weights; reduce all
// partials in double; write the 3 output scalars.
// ---------------------------------------------------------------------------
__global__ __launch_bounds__(256) void final_kernel(const int* __restrict__ tgt,
                                                    const double* __restrict__ ws,
                                                    float* __restrict__ out) {
    __shared__ int hist[NCLS];
    __shared__ double r0[256], r1[256], r2[256], rc[256];
    const int tid = threadIdx.x;

    for (int i = tid; i < NCLS; i += 256) hist[i] = 0;
    __syncthreads();
    for (int i = tid; i < NPTS; i += 256) atomicAdd(&hist[tgt[i]], 1);
    __syncthreads();

    double a = 0.0, s = 0.0, t = 0.0, c = 0.0;
    for (int i = tid; i < NPAIRS; i += 256) {
        a += ws[i];
        s += ws[NPAIRS + i];
        t += ws[2 * NPAIRS + i];
    }
    for (int i = tid; i < CLS_BLOCKS; i += 256) c += ws[WS_CLS + i];
    r0[tid] = a; r1[tid] = s; r2[tid] = t; rc[tid] = c;
    __syncthreads();
    for (int sdt = 128; sdt > 0; sdt >>= 1) {
        if (tid < sdt) {
            r0[tid] += r0[tid + sdt];
            r1[tid] += r1[tid + sdt];
            r2[tid] += r2[tid + sdt];
            rc[tid] += rc[tid + sdt];
        }
        __syncthreads();
    }

    if (tid == 0) {
        double n_pos = 0.0;
        for (int k = 0; k < NCLS; k++) {
            double cc = (double)hist[k];
            n_pos += cc * cc;
        }
        const double Nd = (double)NPTS;
        double S1 = n_pos - Nd;
        double S0 = Nd * Nd - n_pos;
        if (S0 == 0.0) S0 = 1.0;
        if (S1 == 0.0) S1 = 1.0;
        const double S = S0 + S1;
        // lower-triangle weighted sum: neg = w0*(SP_all - SP_same), pos = w1*(SP_same - TH_same)
        const double sum_lower = (S / S0) * (r0[0] - r1[0]) + (S / S1) * (r1[0] - r2[0]);
        const double count = Nd * (Nd - 1.0) * 0.5;
        const double hash_loss = sum_lower / count;
        const double cls_loss  = rc[0] / Nd;
        const double loss = 1.0 * cls_loss + 0.01 * hash_loss;
        out[0] = (float)hash_loss;
        out[1] = (float)cls_loss;
        out[2] = (float)loss;
    }
}

// ---------------------------------------------------------------------------
extern "C" void kernel_launch(void* const* d_in, const int* in_sizes, int n_in,
                              void* d_out, int out_size, void* d_ws, size_t ws_size,
                              hipStream_t stream) {
    const float* H   = (const float*)d_in[0];   // hash_out [8192,64]
    const float* X   = (const float*)d_in[1];   // cls_out  [8192,101]
    const int*   tgt = (const int*)d_in[2];     // target   [8192]
    float* out = (float*)d_out;
    double* wsd = (double*)d_ws;

    cls_kernel<<<CLS_BLOCKS, 256, 0, stream>>>(X, tgt, wsd);
    hash_pair_kernel<<<NPAIRS, 256, 0, stream>>>(H, tgt, wsd);
    final_kernel<<<1, 256, 0, stream>>>(tgt, wsd, out);
}

// Round 3
// 46.383 us; speedup vs baseline: 4.9335x; 1.1559x over previous
//
#include <hip/hip_runtime.h>
#include <math.h>

#define NPTS   8192
#define BITS   64
#define NCLS   101
#define TILE   128
#define NT     (NPTS / TILE)            // 64
#define NPAIRS (NT * (NT + 1) / 2)      // 2080
#define WS_CLS (3 * NPAIRS)
#define SQH    0.70710678f              // sqrt(0.5): staged h*SQH -> acc = <hi,hj>/2 = theta

// ws layout (doubles):
//   [0, NPAIRS)            : SP_all  partials (softplus over valid i<j in tile)
//   [NPAIRS, 2*NPAIRS)     : SP_same partials (softplus over same-class i<j)
//   [2*NPAIRS, 3*NPAIRS)   : TH_same partials (theta over same-class i<j)
//   [WS_CLS, WS_CLS+NPAIRS): cls NLL partials (4 rows per block)

typedef short    bf16x8   __attribute__((ext_vector_type(8)));
typedef unsigned short ushort8v __attribute__((ext_vector_type(8)));
typedef float    f32x16   __attribute__((ext_vector_type(16)));

__device__ __forceinline__ unsigned short f2bf(float f) {
    unsigned int u = __float_as_uint(f);
    u += 0x7FFFu + ((u >> 16) & 1u);     // RNE (inputs finite)
    return (unsigned short)(u >> 16);
}

// ---------------------------------------------------------------------------
// Fused kernel: one 128x128 upper-tri tile of theta = H H^T / 2 via bf16 MFMA
// (scale folded into staging), softplus epilogue with diag/offdiag variants,
// plus 4 rows of the log-softmax NLL per block (one row per wave).
// ---------------------------------------------------------------------------
__global__ __launch_bounds__(256) void hash_cls_kernel(const float* __restrict__ H,
                                                       const float* __restrict__ X,
                                                       const int* __restrict__ tgt,
                                                       double* __restrict__ ws) {
    __shared__ unsigned short As[TILE * BITS];   // 16 KiB, swizzled bf16
    __shared__ unsigned short Bs[TILE * BITS];   // 16 KiB
    __shared__ int tI[TILE];
    __shared__ int tJ[TILE];
    __shared__ float red[16];

    const int tid = threadIdx.x;

    // map linear block id -> (ti, tj) with ti <= tj
    const int p = blockIdx.x;
    int ti;
    {
        float disc = (2.0f * NT + 1.0f) * (2.0f * NT + 1.0f) - 8.0f * (float)p;
        ti = (int)(((2.0f * NT + 1.0f) - sqrtf(disc)) * 0.5f);
        if (ti < 0) ti = 0;
        if (ti >= NT) ti = NT - 1;
        while (ti > 0 && (ti * NT - ti * (ti - 1) / 2) > p) ti--;
        while ((ti + 1) * NT - (ti + 1) * ti / 2 <= p) ti++;
    }
    const int base = ti * NT - ti * (ti - 1) / 2;
    const int tj = ti + (p - base);
    const int i0 = ti * TILE;
    const int j0 = tj * TILE;
    const bool diag = (ti == tj);

    if (tid < TILE) { tI[tid] = tgt[i0 + tid]; tJ[tid] = tgt[j0 + tid]; }

    // stage both tiles as bf16*sqrt(0.5): 2048 chunks of 8 elements (16B LDS)
#pragma unroll
    for (int it = 0; it < 8; ++it) {
        int idx  = tid + it * 256;
        int half = idx >> 10;          // 0 -> A rows, 1 -> B rows
        int lid  = idx & 1023;
        int row  = lid >> 3;
        int c    = lid & 7;
        const float* src = H + (size_t)((half ? j0 : i0) + row) * BITS + c * 8;
        float4 f0 = *(const float4*)src;
        float4 f1 = *(const float4*)(src + 4);
        ushort8v v;
        v[0] = f2bf(f0.x * SQH); v[1] = f2bf(f0.y * SQH);
        v[2] = f2bf(f0.z * SQH); v[3] = f2bf(f0.w * SQH);
        v[4] = f2bf(f1.x * SQH); v[5] = f2bf(f1.y * SQH);
        v[6] = f2bf(f1.z * SQH); v[7] = f2bf(f1.w * SQH);
        unsigned short* dst = half ? Bs : As;
        *(ushort8v*)&dst[row * BITS + ((c ^ (row & 7)) * 8)] = v;
    }
    __syncthreads();

    const int lane = tid & 63;
    const int wave = tid >> 6;
    const int wr = wave >> 1, wc = wave & 1;   // 2x2 wave grid, 64x64 each
    const int lrow = lane & 31;
    const int hi = lane >> 5;

    f32x16 acc[2][2];
#pragma unroll
    for (int a = 0; a < 2; ++a)
#pragma unroll
        for (int b = 0; b < 2; ++b)
#pragma unroll
            for (int e = 0; e < 16; ++e) acc[a][b][e] = 0.f;

    auto ldfrag = [](const unsigned short* S, int row, int chunk) -> bf16x8 {
        ushort8v r = *(const ushort8v*)&S[row * BITS + ((chunk ^ (row & 7)) * 8)];
        return __builtin_bit_cast(bf16x8, r);
    };

#pragma unroll
    for (int ks = 0; ks < 4; ++ks) {
        const int ch = ks * 2 + hi;
        bf16x8 a0 = ldfrag(As, wr * 64 +      lrow, ch);
        bf16x8 a1 = ldfrag(As, wr * 64 + 32 + lrow, ch);
        bf16x8 b0 = ldfrag(Bs, wc * 64 +      lrow, ch);
        bf16x8 b1 = ldfrag(Bs, wc * 64 + 32 + lrow, ch);
        acc[0][0] = __builtin_amdgcn_mfma_f32_32x32x16_bf16(a0, b0, acc[0][0], 0, 0, 0);
        acc[0][1] = __builtin_amdgcn_mfma_f32_32x32x16_bf16(a0, b1, acc[0][1], 0, 0, 0);
        acc[1][0] = __builtin_amdgcn_mfma_f32_32x32x16_bf16(a1, b0, acc[1][0], 0, 0, 0);
        acc[1][1] = __builtin_amdgcn_mfma_f32_32x32x16_bf16(a1, b1, acc[1][1], 0, 0, 0);
    }

    // epilogue: C/D layout col = lane&31, row = (reg&3) + 8*(reg>>2) + 4*(lane>>5)
    float s_all = 0.f, s_same = 0.f, t_same = 0.f;
    if (!diag) {
#pragma unroll
        for (int it = 0; it < 2; ++it) {
            int trow[16];
#pragma unroll
            for (int r = 0; r < 16; ++r)
                trow[r] = tI[wr * 64 + it * 32 + (r & 3) + 8 * (r >> 2) + 4 * hi];
#pragma unroll
            for (int jt = 0; jt < 2; ++jt) {
                const int tc = tJ[wc * 64 + jt * 32 + lrow];
#pragma unroll
                for (int r = 0; r < 16; ++r) {
                    float a  = acc[it][jt][r];        // theta
                    float e  = __expf(a);
                    float lg = __logf(1.0f + e);      // softplus
                    s_all += lg;
                    float m = (trow[r] == tc) ? 1.0f : 0.0f;
                    s_same = fmaf(m, lg, s_same);
                    t_same = fmaf(m, a,  t_same);
                }
            }
        }
    } else {
#pragma unroll
        for (int it = 0; it < 2; ++it) {
            int trow[16], grow[16];
#pragma unroll
            for (int r = 0; r < 16; ++r) {
                int lr = wr * 64 + it * 32 + (r & 3) + 8 * (r >> 2) + 4 * hi;
                grow[r] = i0 + lr;
                trow[r] = tI[lr];
            }
#pragma unroll
            for (int jt = 0; jt < 2; ++jt) {
                const int lc = wc * 64 + jt * 32 + lrow;
                const int gcol = j0 + lc;
                const int tc = tJ[lc];
#pragma unroll
                for (int r = 0; r < 16; ++r) {
                    float a  = acc[it][jt][r];
                    float e  = __expf(a);
                    float lg = __logf(1.0f + e);
                    bool valid = gcol > grow[r];
                    bool same  = valid && (trow[r] == tc);
                    s_all  += valid ? lg : 0.f;
                    s_same += same  ? lg : 0.f;
                    t_same += same  ? a  : 0.f;
                }
            }
        }
    }

#pragma unroll
    for (int d = 32; d > 0; d >>= 1) {
        s_all  += __shfl_xor(s_all,  d, 64);
        s_same += __shfl_xor(s_same, d, 64);
        t_same += __shfl_xor(t_same, d, 64);
    }
    if (lane == 0) { red[wave] = s_all; red[4 + wave] = s_same; red[8 + wave] = t_same; }

    // fused cls: block p handles rows 4p .. 4p+3, one row per wave
    {
        const int row = p * 4 + wave;
        float nll = 0.f;
        if (row < NPTS) {
            const float* x = X + (size_t)row * NCLS;
            float x1 = x[lane];
            float x2 = (lane + 64 < NCLS) ? x[lane + 64] : -INFINITY;
            float m = fmaxf(x1, x2);
#pragma unroll
            for (int d = 32; d > 0; d >>= 1) m = fmaxf(m, __shfl_xor(m, d, 64));
            float e = expf(x1 - m) + ((lane + 64 < NCLS) ? expf(x2 - m) : 0.f);
#pragma unroll
            for (int d = 32; d > 0; d >>= 1) e += __shfl_xor(e, d, 64);
            if (lane == 0) nll = m + logf(e) - x[tgt[row]];
        }
        if (lane == 0) red[12 + wave] = nll;
    }
    __syncthreads();
    if (tid == 0) {
        ws[p]              = (double)red[0]  + (double)red[1]  + (double)red[2]  + (double)red[3];
        ws[NPAIRS + p]     = (double)red[4]  + (double)red[5]  + (double)red[6]  + (double)red[7];
        ws[2 * NPAIRS + p] = (double)red[8]  + (double)red[9]  + (double)red[10] + (double)red[11];
        ws[WS_CLS + p]     = (double)red[12] + (double)red[13] + (double)red[14] + (double)red[15];
    }
}

// ---------------------------------------------------------------------------
// Finalize: class histogram -> n_pos -> S0/S1 weights; reduce partials in
// double; write the 3 output scalars.
// ---------------------------------------------------------------------------
__global__ __launch_bounds__(256) void final_kernel(const int* __restrict__ tgt,
                                                    const double* __restrict__ ws,
                                                    float* __restrict__ out) {
    __shared__ int hist[NCLS];
    __shared__ double r0[256], r1[256], r2[256], rc[256];
    const int tid = threadIdx.x;

    for (int i = tid; i < NCLS; i += 256) hist[i] = 0;
    __syncthreads();
    for (int i = tid; i < NPTS; i += 256) atomicAdd(&hist[tgt[i]], 1);
    __syncthreads();

    double a = 0.0, s = 0.0, t = 0.0, c = 0.0;
    for (int i = tid; i < NPAIRS; i += 256) {
        a += ws[i];
        s += ws[NPAIRS + i];
        t += ws[2 * NPAIRS + i];
        c += ws[WS_CLS + i];
    }
    r0[tid] = a; r1[tid] = s; r2[tid] = t; rc[tid] = c;
    __syncthreads();
    for (int sdt = 128; sdt > 0; sdt >>= 1) {
        if (tid < sdt) {
            r0[tid] += r0[tid + sdt];
            r1[tid] += r1[tid + sdt];
            r2[tid] += r2[tid + sdt];
            rc[tid] += rc[tid + sdt];
        }
        __syncthreads();
    }

    if (tid == 0) {
        double n_pos = 0.0;
        for (int k = 0; k < NCLS; k++) {
            double cc = (double)hist[k];
            n_pos += cc * cc;
        }
        const double Nd = (double)NPTS;
        double S1 = n_pos - Nd;
        double S0 = Nd * Nd - n_pos;
        if (S0 == 0.0) S0 = 1.0;
        if (S1 == 0.0) S1 = 1.0;
        const double S = S0 + S1;
        // lower-tri weighted sum: neg = w0*(SP_all - SP_same), pos = w1*(SP_same - TH_same)
        const double sum_lower = (S / S0) * (r0[0] - r1[0]) + (S / S1) * (r1[0] - r2[0]);
        const double count = Nd * (Nd - 1.0) * 0.5;
        const double hash_loss = sum_lower / count;
        const double cls_loss  = rc[0] / Nd;
        const double loss = 1.0 * cls_loss + 0.01 * hash_loss;
        out[0] = (float)hash_loss;
        out[1] = (float)cls_loss;
        out[2] = (float)loss;
    }
}

// ---------------------------------------------------------------------------
extern "C" void kernel_launch(void* const* d_in, const int* in_sizes, int n_in,
                              void* d_out, int out_size, void* d_ws, size_t ws_size,
                              hipStream_t stream) {
    const float* H   = (const float*)d_in[0];   // hash_out [8192,64]
    const float* X   = (const float*)d_in[1];   // cls_out  [8192,101]
    const int*   tgt = (const int*)d_in[2];     // target   [8192]
    float* out = (float*)d_out;
    double* wsd = (double*)d_ws;

    hash_cls_kernel<<<NPAIRS, 256, 0, stream>>>(H, X, tgt, wsd);
    final_kernel<<<1, 256, 0, stream>>>(tgt, wsd, out);
}